// Round 4
// baseline (284.720 us; speedup 1.0000x reference)
//
#include <hip/hip_runtime.h>

// TemporalLSTM via split-bf16 MFMA, round 4 (gfx950).
// x[16384,200,5] fp32 -> LSTM(H=32, gates i,f,g,o) -> h_200 @ W_fc^T + b_fc -> out[16384,2]
//
// Structure (from round 3): 1024 blocks x 128 threads (2 waves), block owns 16 batches,
// gate tiles split by j-half across the 2 waves (wave wv: columns j in [16wv,16wv+16)).
// Round-4 deltas (issue-bound at ~60%: cut instruction count + shorten chain):
//  - x-projection mfma (h-independent) pipelined one step ahead: xn[g] computed during
//    step t, used as the accumulator init of step t+1 -> post-barrier chain is
//    ds_read h -> 3 mfma -> pointwise. No acc zero-init movs.
//  - constant A-frag quads (k16 bias-lo row / zero) live as xbuf columns 32/33:
//    column index is loop-invariant, every lane does one plain ds_read_b128 per step.
//  - pointwise in f32x4 vector form (v_pk_* for mul/add/fma; exp2/rcp stay scalar).
// Numerics identical to round 2/3 (split-bf16 hi+lo GEMM, fp32 accumulate).

typedef __bf16 bf16x8 __attribute__((ext_vector_type(8)));
typedef float  f32x4  __attribute__((ext_vector_type(4)));
typedef unsigned int u32;

constexpr int kT = 200, kIN = 5, kH = 32;
constexpr int CT   = 40;   // timesteps of x staged per phase (200 = 5*40)
constexpr int HSTR = 40;   // bf16 elements per h row (80 B, 16B-aligned b128 reads)

union FragU { bf16x8 v; __bf16 b[8]; unsigned short s[8]; u32 u[4]; uint4 q4; };

__device__ __forceinline__ unsigned short bfbits(__bf16 b) {
    union { __bf16 b; unsigned short s; } u; u.b = b; return u.s;
}
__device__ __forceinline__ void split2(float x, __bf16& hi, __bf16& lo) {
    hi = (__bf16)x;                 // RNE cvt
    lo = (__bf16)(x - (float)hi);   // residual, |lo| <= 2^-9 |x|
}

__device__ __forceinline__ f32x4 sigm4(f32x4 z) {
    f32x4 t = z * -1.4426950408889634f;
    f32x4 e;
#pragma unroll
    for (int i = 0; i < 4; ++i) e[i] = __builtin_amdgcn_exp2f(t[i]);
    e = e + 1.0f;
    f32x4 r;
#pragma unroll
    for (int i = 0; i < 4; ++i) r[i] = __builtin_amdgcn_rcpf(e[i]);
    return r;
}
__device__ __forceinline__ f32x4 tanh4(f32x4 z) {
    f32x4 t = z * -2.8853900817779268f;
    f32x4 e;
#pragma unroll
    for (int i = 0; i < 4; ++i) e[i] = __builtin_amdgcn_exp2f(t[i]);
    e = e + 1.0f;
    f32x4 r;
#pragma unroll
    for (int i = 0; i < 4; ++i) r[i] = __builtin_amdgcn_rcpf(e[i]);
    return r * 2.0f - 1.0f;
}

__global__ __launch_bounds__(128) void lstm_mfma3(
    const float* __restrict__ x,     // [B,200,5]
    const float* __restrict__ W_ih,  // [128,5]
    const float* __restrict__ W_hh,  // [128,32]
    const float* __restrict__ b_ih,  // [128]
    const float* __restrict__ b_hh,  // [128]
    const float* __restrict__ W_fc,  // [2,32]
    const float* __restrict__ b_fc,  // [2]
    float* __restrict__ out)         // [B,2]
{
    __shared__ uint4 xbuf[CT][34];                       // cols 0..31 x A-frags, 32/33 const
    __shared__ __align__(16) __bf16 hbh[2][16 * HSTR];   // h hi, ping-pong
    __shared__ __align__(16) __bf16 hbl[2][16 * HSTR];   // h lo, ping-pong

    const int tid  = threadIdx.x;
    const int wv   = tid >> 6;        // wave: j-half 0 or 1
    const int lane = tid & 63;
    const int n16  = lane & 15;
    const int q    = lane >> 4;
    const int b0   = blockIdx.x * 16;

    // ---- weight B-frags resident in VGPRs: this wave's 4 tiles {i,f,g,o} ----
    bf16x8 whhh[4], whhl[4], wihf[4];
#pragma unroll
    for (int g = 0; g < 4; ++g) {
        const int t = 2 * g + wv;          // tile index 0..7 (gate-major, j-half minor)
        const int r = t * 16 + n16;        // gate row 0..127
        FragU H, L;
#pragma unroll
        for (int j = 0; j < 8; ++j)
            split2(W_hh[r * kH + q * 8 + j], H.b[j], L.b[j]);
        whhh[g] = H.v; whhl[g] = L.v;

        float wr[5];
#pragma unroll
        for (int i = 0; i < 5; ++i) wr[i] = W_ih[r * kIN + i];
        __bf16 bh, bl;
        split2(b_ih[r] + b_hh[r], bh, bl);

        FragU F;
        F.u[0] = F.u[1] = F.u[2] = F.u[3] = 0u;
        if (q == 0) {
#pragma unroll
            for (int i = 0; i < 5; ++i) F.b[i] = (__bf16)wr[i];        // k0..4: Wih_hi
#pragma unroll
            for (int i = 0; i < 3; ++i) F.b[5 + i] = (__bf16)wr[i];    // k5..7: Wih_hi
        } else if (q == 1) {
            F.b[0] = (__bf16)wr[3];                                    // k8
            F.b[1] = (__bf16)wr[4];                                    // k9
#pragma unroll
            for (int i = 0; i < 5; ++i) {                              // k10..14: Wih_lo
                __bf16 hb, lb; split2(wr[i], hb, lb);
                F.b[2 + i] = lb;
            }
            F.b[7] = bh;                                               // k15: bias_hi
        } else if (q == 2) {
            F.b[0] = bl;                                               // k16: bias_lo
        }
        wihf[g] = F.v;
    }

    // ---- init: zero parity-0 h, write constant xbuf columns 32/33 ----
    {
        u32* z0 = (u32*)&hbh[0][0];
        u32* z1 = (u32*)&hbl[0][0];
        for (int i = tid; i < (16 * HSTR) / 2; i += 128) { z0[i] = 0u; z1[i] = 0u; }
        for (int t2 = tid; t2 < CT; t2 += 128) {
            xbuf[t2][32] = make_uint4(0x3F80u, 0u, 0u, 0u);  // quad2: k16 A=1.0 (bf16)
            xbuf[t2][33] = make_uint4(0u, 0u, 0u, 0u);       // quad3: zeros
        }
    }

    const int col = (q < 2) ? (n16 * 2 + q) : (30 + q);      // loop-invariant xf column
    const int hro = n16 * HSTR + q * 8;                      // A-frag read offset
    const int hwo = (q * 4) * HSTR + n16 + 16 * wv;          // h write offset (+ r*HSTR)

    f32x4 c4 = {0.f, 0.f, 0.f, 0.f};
    const f32x4 zf4 = {0.f, 0.f, 0.f, 0.f};

    for (int phase = 0; phase < kT / CT; ++phase) {
        // ---- stage CT steps of x as ready-made A-frags (128 threads) ----
        {
            const int mm = tid >> 3, pp = tid & 7;           // batch row, 5-step chunk
            const float* xrow = x + (size_t)(b0 + mm) * (kT * kIN)
                                  + (size_t)(phase * CT + pp * 5) * kIN;
            float xv[25];
#pragma unroll
            for (int i = 0; i < 25; ++i) xv[i] = xrow[i];
#pragma unroll
            for (int s5 = 0; s5 < 5; ++s5) {
                u32 xh[5], xl[5];
#pragma unroll
                for (int i = 0; i < 5; ++i) {
                    __bf16 hb, lb; split2(xv[s5 * 5 + i], hb, lb);
                    xh[i] = bfbits(hb); xl[i] = bfbits(lb);
                }
                uint4 f0 = make_uint4(xh[0] | (xh[1] << 16),
                                      xh[2] | (xh[3] << 16),
                                      xh[4] | (xl[0] << 16),
                                      xl[1] | (xl[2] << 16));
                uint4 f1 = make_uint4(xl[3] | (xl[4] << 16),
                                      xh[0] | (xh[1] << 16),
                                      xh[2] | (xh[3] << 16),
                                      xh[4] | (0x3F80u << 16));   // k15: A = 1.0
                const int tc = pp * 5 + s5;
                xbuf[tc][mm * 2 + 0] = f0;
                xbuf[tc][mm * 2 + 1] = f1;
            }
        }
        __syncthreads();   // covers init (phase 0) and xbuf staging

        // xacc for the first step of this phase
        FragU xg; xg.q4 = xbuf[0][col];
        f32x4 xn[4];
#pragma unroll
        for (int g = 0; g < 4; ++g)
            xn[g] = __builtin_amdgcn_mfma_f32_16x16x32_bf16(xg.v, wihf[g], zf4, 0, 0, 0);

#pragma unroll 1
        for (int tc = 0; tc < CT; ++tc) {
            const int pr = tc & 1, pw = pr ^ 1;

            bf16x8 AH = *(const bf16x8*)(&hbh[pr][hro]);
            bf16x8 AL = *(const bf16x8*)(&hbl[pr][hro]);

            // h-dependent chain: 3 mfma per tile, init = precomputed x-proj+bias
            f32x4 acc[4];
#pragma unroll
            for (int g = 0; g < 4; ++g) {
                f32x4 a = __builtin_amdgcn_mfma_f32_16x16x32_bf16(AH, whhh[g], xn[g], 0, 0, 0);
                a = __builtin_amdgcn_mfma_f32_16x16x32_bf16(AH, whhl[g], a, 0, 0, 0);
                a = __builtin_amdgcn_mfma_f32_16x16x32_bf16(AL, whhh[g], a, 0, 0, 0);
                acc[g] = a;
            }

            // pipeline next step's x-proj (h-independent, fills pointwise latency)
            const int tn = (tc + 1 < CT) ? tc + 1 : 0;
            FragU xg2; xg2.q4 = xbuf[tn][col];
#pragma unroll
            for (int g = 0; g < 4; ++g)
                xn[g] = __builtin_amdgcn_mfma_f32_16x16x32_bf16(xg2.v, wihf[g], zf4, 0, 0, 0);

            // pointwise (f32x4 vector form -> v_pk_* for non-trans ops)
            f32x4 iv = sigm4(acc[0]);
            f32x4 fv = sigm4(acc[1]);
            f32x4 gv = tanh4(acc[2]);
            f32x4 ov = sigm4(acc[3]);
            c4 = fv * c4 + iv * gv;
            f32x4 h4 = ov * tanh4(c4);

#pragma unroll
            for (int r = 0; r < 4; ++r) {
                __bf16 hh, hl;
                split2(h4[r], hh, hl);
                hbh[pw][hwo + r * HSTR] = hh;
                hbl[pw][hwo + r * HSTR] = hl;
            }
            __syncthreads();   // writes(t+1) -> reads(t+1)
        }
    }

    // ---- epilogue: final h is in parity 0 (200 even). out = h.W_fc + b_fc ----
    if (tid < 32) {
        const int m = tid >> 1, o = tid & 1;
        float s = b_fc[o];
#pragma unroll
        for (int j = 0; j < kH; ++j) {
            float hv = (float)hbh[0][m * HSTR + j] + (float)hbl[0][m * HSTR + j];
            s = fmaf(hv, W_fc[o * kH + j], s);
        }
        out[(size_t)(b0 + m) * 2 + o] = s;
    }
}

extern "C" void kernel_launch(void* const* d_in, const int* in_sizes, int n_in,
                              void* d_out, int out_size, void* d_ws, size_t ws_size,
                              hipStream_t stream) {
    const float* x    = (const float*)d_in[0];
    const float* W_ih = (const float*)d_in[1];
    const float* W_hh = (const float*)d_in[2];
    const float* b_ih = (const float*)d_in[3];
    const float* b_hh = (const float*)d_in[4];
    const float* W_fc = (const float*)d_in[5];
    const float* b_fc = (const float*)d_in[6];
    float* out = (float*)d_out;

    // 16384 batches / 16 per block = 1024 blocks x 128 threads (2 waves)
    hipLaunchKernelGGL(lstm_mfma3, dim3(1024), dim3(128), 0, stream,
                       x, W_ih, W_hh, b_ih, b_hh, W_fc, b_fc, out);
}

// Round 5
// 275.094 us; speedup vs baseline: 1.0350x; 1.0350x over previous
//
#include <hip/hip_runtime.h>

// TemporalLSTM round 5 (gfx950): fully in-register recurrence.
// x[16384,200,5] fp32 -> LSTM(H=32, gates i,f,g,o) -> h_200 @ W_fc^T + b_fc -> out[16384,2]
//
// Key idea: A = WEIGHTS, B = ACTIVATIONS (swap of rounds 2-4). With gate rows
// permuted across 8 tiles as: tile t = (j-half hb = t>>2, gate g = t&3),
//   tile row m  <->  original gate row R = 32*g + jmap,  jmap = 8*(m>>2) + 4*hb + (m&3)
// the MFMA C/D layout (m = q*4+r, n = lane&15) gives lane (n,q):
//   acc[hb*4+g][r] = gate g, batch n, j = 8q + 4*hb + r
// i.e. all four gates of (n, j) for j in {8q..8q+7} are IN-LANE, and the next
// step's h B-frag (B[k][n]: n = lane&15, k = q*8+kk -> h[n][8q+kk]) is exactly
// the lane's own pointwise output. No LDS round-trip, no barriers, no cross-lane:
// the recurrence lives in VGPRs. 1024 single-wave blocks (16 batches each).
//
// Numerics identical to rounds 2-4: split-bf16 (hi + residual lo) GEMM keeping
// Whi*Bhi + Whi*Blo + Wlo*Bhi (fp32 accumulate), x-proj + bias packed in one
// K<=17 mfma (k0-4: xh*Wih_hi, k5-9: xl*Wih_hi, k10-14: xh*Wih_lo,
// k15: 1*bias_hi, k16 (quad2): 1*bias_lo), exp2/rcp sigmoid+tanh.

typedef __bf16 bf16x8 __attribute__((ext_vector_type(8)));
typedef float  f32x4  __attribute__((ext_vector_type(4)));
typedef unsigned int u32;

constexpr int kT = 200, kIN = 5, kH = 32;
constexpr int CT = 40;   // timesteps of x staged per phase (200 = 5*40)

union FragU { bf16x8 v; __bf16 b[8]; unsigned short s[8]; u32 u[4]; uint4 q4; };

__device__ __forceinline__ unsigned short bfbits(__bf16 b) {
    union { __bf16 b; unsigned short s; } u; u.b = b; return u.s;
}
__device__ __forceinline__ void split2(float x, __bf16& hi, __bf16& lo) {
    hi = (__bf16)x;                 // RNE cvt
    lo = (__bf16)(x - (float)hi);   // residual, |lo| <= 2^-9 |x|
}
__device__ __forceinline__ float sigm(float z) {
    return __builtin_amdgcn_rcpf(1.0f + __builtin_amdgcn_exp2f(-1.4426950408889634f * z));
}
__device__ __forceinline__ float tanhv(float z) {
    return fmaf(2.0f,
        __builtin_amdgcn_rcpf(1.0f + __builtin_amdgcn_exp2f(-2.8853900817779268f * z)),
        -1.0f);
}

__global__ __launch_bounds__(64) void lstm_reg(
    const float* __restrict__ x,     // [B,200,5]
    const float* __restrict__ W_ih,  // [128,5]
    const float* __restrict__ W_hh,  // [128,32]
    const float* __restrict__ b_ih,  // [128]
    const float* __restrict__ b_hh,  // [128]
    const float* __restrict__ W_fc,  // [2,32]
    const float* __restrict__ b_fc,  // [2]
    float* __restrict__ out)         // [B,2]
{
    __shared__ uint4 xbuf[CT][34];   // cols 0..31: x B-frags; 32/33: const quads

    const int lane = threadIdx.x;    // single-wave block
    const int n16  = lane & 15;
    const int q    = lane >> 4;
    const int b0   = blockIdx.x * 16;

    // ---- weight A-frags resident in VGPRs (A[m][k]: m = lane&15, k = q*8+j) ----
    // tile t8 = hb*4 + g; lane row m = n16; element j -> k = 8q+j
    bf16x8 whhA_h[8], whhA_l[8], wihA[8];
#pragma unroll
    for (int t8 = 0; t8 < 8; ++t8) {
        const int g  = t8 & 3, hb = t8 >> 2;
        const int R  = g * 32 + 8 * (n16 >> 2) + 4 * hb + (n16 & 3);  // original gate row
        FragU H, L;
#pragma unroll
        for (int j = 0; j < 8; ++j)
            split2(W_hh[R * kH + q * 8 + j], H.b[j], L.b[j]);
        whhA_h[t8] = H.v; whhA_l[t8] = L.v;

        float wr[5];
#pragma unroll
        for (int i = 0; i < 5; ++i) wr[i] = W_ih[R * kIN + i];
        __bf16 bh, bl;
        split2(b_ih[R] + b_hh[R], bh, bl);

        FragU F;
        F.u[0] = F.u[1] = F.u[2] = F.u[3] = 0u;
        if (q == 0) {                       // k0..7
#pragma unroll
            for (int i = 0; i < 5; ++i) F.b[i] = (__bf16)wr[i];       // k0..4: Wih_hi
#pragma unroll
            for (int i = 0; i < 3; ++i) F.b[5 + i] = (__bf16)wr[i];   // k5..7: Wih_hi(0..2)
        } else if (q == 1) {                // k8..15
            F.b[0] = (__bf16)wr[3];                                   // k8:  Wih_hi(3)
            F.b[1] = (__bf16)wr[4];                                   // k9:  Wih_hi(4)
#pragma unroll
            for (int i = 0; i < 5; ++i) {                             // k10..14: Wih_lo
                __bf16 hbb, lbb; split2(wr[i], hbb, lbb);
                F.b[2 + i] = lbb;
            }
            F.b[7] = bh;                                              // k15: bias_hi
        } else if (q == 2) {
            F.b[0] = bl;                                              // k16: bias_lo
        }
        wihA[t8] = F.v;
    }

    // ---- const x-frag quads (written once; only read after first staging sync) ----
    for (int t2 = lane; t2 < CT; t2 += 64) {
        xbuf[t2][32] = make_uint4(0x3F80u, 0u, 0u, 0u);   // quad2: k16 B=1.0 (bf16)
        xbuf[t2][33] = make_uint4(0u, 0u, 0u, 0u);        // quad3: zeros
    }

    const int col = (q < 2) ? (n16 * 2 + q) : (30 + q);   // loop-invariant frag column
    const f32x4 zf4 = {0.f, 0.f, 0.f, 0.f};

    // recurrence state, fully in registers
    float c8[8] = {0.f, 0.f, 0.f, 0.f, 0.f, 0.f, 0.f, 0.f};
    float hf[8] = {0.f, 0.f, 0.f, 0.f, 0.f, 0.f, 0.f, 0.f};
    FragU Bh, Bl;                                          // h as bf16 hi/lo B-frags
    Bh.u[0] = Bh.u[1] = Bh.u[2] = Bh.u[3] = 0u;
    Bl.u[0] = Bl.u[1] = Bl.u[2] = Bl.u[3] = 0u;

    f32x4 xn[8];                                           // pipelined x-proj + bias

    for (int phase = 0; phase < kT / CT; ++phase) {
        // ---- stage CT steps of x as ready-made B-frags (64 lanes) ----
        {
            const int mm = lane >> 2, pp = lane & 3;       // batch row, 10-step chunk
            const float2* xr2 = (const float2*)(x + (size_t)(b0 + mm) * (kT * kIN)
                                                  + (size_t)(phase * CT + pp * 10) * kIN);
            float xv[50];
#pragma unroll
            for (int i = 0; i < 25; ++i) {
                float2 v = xr2[i];
                xv[2 * i] = v.x; xv[2 * i + 1] = v.y;
            }
#pragma unroll
            for (int s5 = 0; s5 < 10; ++s5) {
                u32 xh[5], xl[5];
#pragma unroll
                for (int i = 0; i < 5; ++i) {
                    __bf16 hbb, lbb; split2(xv[s5 * 5 + i], hbb, lbb);
                    xh[i] = bfbits(hbb); xl[i] = bfbits(lbb);
                }
                uint4 f0 = make_uint4(xh[0] | (xh[1] << 16),
                                      xh[2] | (xh[3] << 16),
                                      xh[4] | (xl[0] << 16),
                                      xl[1] | (xl[2] << 16));
                uint4 f1 = make_uint4(xl[3] | (xl[4] << 16),
                                      xh[0] | (xh[1] << 16),
                                      xh[2] | (xh[3] << 16),
                                      xh[4] | (0x3F80u << 16));   // k15: B = 1.0
                const int tc = pp * 10 + s5;
                xbuf[tc][mm * 2 + 0] = f0;
                xbuf[tc][mm * 2 + 1] = f1;
            }
        }
        __syncthreads();   // single-wave block: compiles to the needed lgkmcnt wait

        // x-proj for the first step of this phase
        {
            FragU xg; xg.q4 = xbuf[0][col];
#pragma unroll
            for (int t8 = 0; t8 < 8; ++t8)
                xn[t8] = __builtin_amdgcn_mfma_f32_16x16x32_bf16(wihA[t8], xg.v, zf4, 0, 0, 0);
        }

#pragma unroll 1
        for (int tc = 0; tc < CT; ++tc) {
            // h-dependent GEMM: 3 mfma per tile, acc init = precomputed x-proj+bias
            f32x4 acc[8];
#pragma unroll
            for (int t8 = 0; t8 < 8; ++t8) {
                f32x4 a = __builtin_amdgcn_mfma_f32_16x16x32_bf16(whhA_h[t8], Bh.v, xn[t8], 0, 0, 0);
                a = __builtin_amdgcn_mfma_f32_16x16x32_bf16(whhA_h[t8], Bl.v, a, 0, 0, 0);
                a = __builtin_amdgcn_mfma_f32_16x16x32_bf16(whhA_l[t8], Bh.v, a, 0, 0, 0);
                acc[t8] = a;
            }

            // prefetch next step's x-proj (h-independent; tc=39's result is
            // recomputed fresh at the next phase top, so the dummy is harmless)
            {
                const int tn = (tc + 1 < CT) ? tc + 1 : 0;
                FragU xg; xg.q4 = xbuf[tn][col];
#pragma unroll
                for (int t8 = 0; t8 < 8; ++t8)
                    xn[t8] = __builtin_amdgcn_mfma_f32_16x16x32_bf16(wihA[t8], xg.v, zf4, 0, 0, 0);
            }

            // pointwise, fully in-lane: jj -> (hb = jj>>2, r = jj&3), j = 8q+4*hb+r...
            // acc[hb*4+g][r] = gate g of (batch n16, this lane's jj-th j)
#pragma unroll
            for (int jj = 0; jj < 8; ++jj) {
                const int hb = jj >> 2, r = jj & 3;
                float iv = sigm (acc[hb * 4 + 0][r]);
                float fv = sigm (acc[hb * 4 + 1][r]);
                float gv = tanhv(acc[hb * 4 + 2][r]);
                float ov = sigm (acc[hb * 4 + 3][r]);
                float cn = fmaf(fv, c8[jj], iv * gv);
                c8[jj] = cn;
                float hn = ov * tanhv(cn);
                hf[jj] = hn;
                split2(hn, Bh.b[jj], Bl.b[jj]);   // next step's B-frag, in-lane
            }
        }
    }

    // ---- epilogue: out[b][o] = h . W_fc[o] + b_fc[o] (h = hi+lo exact f32 in hf) ----
    // reuse xbuf as f32 scratch: hfin[n][k] stride 33
    float* hfin = (float*)xbuf;
    __syncthreads();
#pragma unroll
    for (int jj = 0; jj < 8; ++jj)
        hfin[n16 * 33 + q * 8 + jj] = hf[jj];
    __syncthreads();
    if (lane < 32) {
        const int m = lane >> 1, o = lane & 1;
        float s = b_fc[o];
#pragma unroll
        for (int j = 0; j < kH; ++j)
            s = fmaf(hfin[m * 33 + j], W_fc[o * kH + j], s);
        out[(size_t)(b0 + m) * 2 + o] = s;
    }
}

extern "C" void kernel_launch(void* const* d_in, const int* in_sizes, int n_in,
                              void* d_out, int out_size, void* d_ws, size_t ws_size,
                              hipStream_t stream) {
    const float* x    = (const float*)d_in[0];
    const float* W_ih = (const float*)d_in[1];
    const float* W_hh = (const float*)d_in[2];
    const float* b_ih = (const float*)d_in[3];
    const float* b_hh = (const float*)d_in[4];
    const float* W_fc = (const float*)d_in[5];
    const float* b_fc = (const float*)d_in[6];
    float* out = (float*)d_out;

    // 16384 batches / 16 per wave = 1024 single-wave blocks
    hipLaunchKernelGGL(lstm_reg, dim3(1024), dim3(64), 0, stream,
                       x, W_ih, W_hh, b_ih, b_hh, W_fc, b_fc, out);
}